// Round 4
// baseline (346.203 us; speedup 1.0000x reference)
//
#include <hip/hip_runtime.h>
#include <stdint.h>

// Problem constants (fixed by setup_inputs)
#define NROWS 8192
#define DDIM 256
#define NSTRIPS 16
#define STRIP_COLS 512     // NROWS / NSTRIPS
#define BN 32              // cols per LDS tile
#define NTILES 16          // STRIP_COLS / BN
#define BM 128             // rows per block (4 waves x 32 rows)

// Scores are computed directly in log2-units: e is scaled by sqrt(log2(e)/0.7)
// so acc = s*log2(e) and exp(s) == exp2(acc). Since s <= 1/0.7, exp2(acc) <= 4.17
// and per-row sums <= ~34k: no overflow, so NO log-sum-exp shift is needed at all.
#define ESCALE 1.4356159f        // sqrt(log2(e)/0.7)
#define LN2F   0.6931471806f
#define NEGBIG (-1e30f)

typedef __attribute__((ext_vector_type(8))) short short8;   // 8 bf16 = 4 VGPRs
typedef __attribute__((ext_vector_type(4))) float f32x4;    // MFMA 16x16 accumulator

typedef __attribute__((address_space(3))) void lds_void;          // LDS ptr for DMA builtin
typedef const __attribute__((address_space(1))) void gl_void;     // global ptr for DMA builtin

__device__ __forceinline__ unsigned short f2bf(float x) {   // RNE float->bf16
  unsigned int u = __float_as_uint(x);
  u += 0x7fffu + ((u >> 16) & 1u);
  return (unsigned short)(u >> 16);
}

// ---------------- Kernel 1: row L2-normalize -> scaled bf16 ----------------
__global__ __launch_bounds__(256) void knorm(const float* __restrict__ emb,
                                             unsigned short* __restrict__ ebf) {
  const int wave = threadIdx.x >> 6, lane = threadIdx.x & 63;
  const int row = blockIdx.x * 4 + wave;              // one wave per row
  const float4 v = *(const float4*)(emb + row * DDIM + lane * 4);
  float ss = v.x * v.x + v.y * v.y + v.z * v.z + v.w * v.w;
#pragma unroll
  for (int off = 1; off < 64; off <<= 1) ss += __shfl_xor(ss, off, 64);
  const float sc = rsqrtf(ss) * ESCALE;
  ushort4 o;
  o.x = f2bf(v.x * sc); o.y = f2bf(v.y * sc);
  o.z = f2bf(v.z * sc); o.w = f2bf(v.w * sc);
  *(ushort4*)(ebf + row * DDIM + lane * 4) = o;
}

// ---------------- Kernel 2: fused sims + masked max / sum-of-exp ----------------
// grid = (NSTRIPS, NROWS/BM) = 1024 blocks. LDS = 2 x 16 KB -> 5 blocks/CU (the
// occupancy that made the 119.9us baseline fast; NBUF=3's 3 blocks/CU was a net
// loss). Depth-1 prefetch: STAGE(t+1) issued right after the barrier overlaps
// compute(t) fully; syncthreads' implicit vmcnt(0) only drains tile t's 4 DMAs
// (t+1 not yet issued), so no in-flight loads are wasted. T5: setprio around the
// MFMA cluster -- with 5 free-running blocks/CU there is wave role-diversity for
// the CU scheduler to arbitrate.
__global__ __launch_bounds__(256, 5) void kmain(const unsigned short* __restrict__ ebf,
                                                const int* __restrict__ cats,
                                                float* __restrict__ posP,
                                                float* __restrict__ sumP) {
  // B tile: BN cols x 256 k as 16B chunks, chunk p = kc*32 + col at byte p*16.
  __shared__ alignas(16) unsigned short smem[2][BN * DDIM];  // 2 x 16 KB
  const int tid = threadIdx.x;
  const int lane = tid & 63, wave = tid >> 6;
  const int lane15 = lane & 15, quad = lane >> 4;
  const int strip = blockIdx.x, rowTile = blockIdx.y;
  const int rowG = rowTile * BM + wave * 32;          // this wave's 32 rows (m=2)
  const int col0 = strip * STRIP_COLS;

  // A fragments for the whole kernel live in registers: a[m][kk] covers
  // rows rowG+m*16+(lane&15), k = kk*32 + quad*8 .. +7   (64 VGPRs)
  short8 a[2][8];
#pragma unroll
  for (int m = 0; m < 2; ++m)
#pragma unroll
    for (int kk = 0; kk < 8; ++kk)
      a[m][kk] = *(const short8*)(ebf + (rowG + m * 16 + lane15) * DDIM + kk * 32 + quad * 8);

  // Per-lane C-layout row categories: row = quad*4 + r (+ m*16)
  int cati[2][4];
#pragma unroll
  for (int m = 0; m < 2; ++m)
#pragma unroll
    for (int r = 0; r < 4; ++r)
      cati[m][r] = cats[rowG + m * 16 + quad * 4 + r];

  // Is this lane the diagonal element (row==col) within a diagonal 16x16 tile?
  bool dlr[4];
#pragma unroll
  for (int r = 0; r < 4; ++r) dlr[r] = (lane15 == quad * 4 + r);

  float pm[2][4], ns[2][4];
#pragma unroll
  for (int m = 0; m < 2; ++m)
#pragma unroll
    for (int r = 0; r < 4; ++r) { pm[m][r] = NEGBIG; ns[m][r] = 0.f; }

  // Async-stage one B tile (1024 16B chunks) into buffer `buf`: 4 DMA per thread.
  // Thread (w,l) takes chunks p = c*256 + w*64 + l; LDS byte = p*16 decomposes as
  // wave-uniform (c*4096 + w*1024) + l*16. Global: kc = c*8 + w*2 + (l>>5), col = l&31.
#define STAGE(t, buf)                                                           \
  {                                                                             \
    const unsigned short* g = ebf +                                             \
        (size_t)(col0 + (t) * BN + (lane & 31)) * DDIM +                        \
        (wave * 2 + (lane >> 5)) * 8;                                           \
    char* lb = (char*)&smem[(buf)][0] + wave * 1024;                            \
    _Pragma("unroll")                                                           \
    for (int c = 0; c < 4; ++c)                                                 \
      __builtin_amdgcn_global_load_lds((gl_void*)(g + c * 64),                  \
                                       (lds_void*)(lb + c * 4096), 16, 0, 0);   \
  }

  STAGE(0, 0);

  for (int t = 0; t < NTILES; ++t) {
    __syncthreads();                       // tile t's DMA drained; prev reads done
    if (t + 1 < NTILES) STAGE(t + 1, (t + 1) & 1);   // overlaps this tile's MFMA
    const char* bb = (const char*)&smem[t & 1][0];
    const int colBase = col0 + t * BN;
    const int cjt[2] = {cats[colBase + lane15], cats[colBase + 16 + lane15]};

#pragma unroll
    for (int nt = 0; nt < 2; ++nt) {
      // Batch the 8 B-fragment reads ahead of the MFMA cluster: one latency +
      // pipelined ds_reads instead of a serial read->use chain.
      short8 b[8];
#pragma unroll
      for (int kk = 0; kk < 8; ++kk)
        b[kk] = *(const short8*)(bb + kk * 2048 + quad * 512 + nt * 256 + lane15 * 16);
      f32x4 acc0 = {0.f, 0.f, 0.f, 0.f}, acc1 = {0.f, 0.f, 0.f, 0.f};
      __builtin_amdgcn_s_setprio(1);       // T5: favor MFMA-issuing wave
#pragma unroll
      for (int kk = 0; kk < 8; ++kk) {
        acc0 = __builtin_amdgcn_mfma_f32_16x16x32_bf16(a[0][kk], b[kk], acc0, 0, 0, 0);
        acc1 = __builtin_amdgcn_mfma_f32_16x16x32_bf16(a[1][kk], b[kk], acc1, 0, 0, 0);
      }
      __builtin_amdgcn_s_setprio(0);
      const int cj = cjt[nt];
      // Wave-uniform: does this 16x16 tile sit on the global diagonal?
      const bool dg0 = (rowG == colBase + nt * 16);
      const bool dg1 = (rowG + 16 == colBase + nt * 16);
#pragma unroll
      for (int m = 0; m < 2; ++m) {
        const bool dg = m ? dg1 : dg0;
#pragma unroll
        for (int r = 0; r < 4; ++r) {
          const float s = m ? acc1[r] : acc0[r];      // score in log2-units
          const float e = __builtin_amdgcn_exp2f(s);
          const bool same = (cj == cati[m][r]);
          float psv = same ? s : NEGBIG;              // positive candidate
          if (dg) psv = dlr[r] ? NEGBIG : psv;        // exclude self (rare branch)
          pm[m][r] = fmaxf(pm[m][r], psv);
          ns[m][r] += same ? 0.f : e;                 // negative sum-of-exp
        }
      }
    }
  }

  // Reduce across the 16 lanes of each quad (they share rows quad*4+r).
#pragma unroll
  for (int off = 1; off < 16; off <<= 1) {
#pragma unroll
    for (int m = 0; m < 2; ++m)
#pragma unroll
      for (int r = 0; r < 4; ++r) {
        pm[m][r] = fmaxf(pm[m][r], __shfl_xor(pm[m][r], off, 64));
        ns[m][r] += __shfl_xor(ns[m][r], off, 64);
      }
  }
  if (lane15 == 0) {
#pragma unroll
    for (int m = 0; m < 2; ++m)
#pragma unroll
      for (int r = 0; r < 4; ++r) {
        const int row = rowG + m * 16 + quad * 4 + r;
        posP[strip * NROWS + row] = pm[m][r];
        sumP[strip * NROWS + row] = ns[m][r];
      }
  }
}

// ---------------- Kernel 3: merge strips, per-row loss, reduce, finalize ----------------
__global__ __launch_bounds__(256) void kmerge(const float* __restrict__ posP,
                                              const float* __restrict__ sumP,
                                              float* __restrict__ acc,
                                              float* __restrict__ out) {
  const int row = blockIdx.x * 256 + threadIdx.x;
  float pm = NEGBIG, ns = 0.f;
#pragma unroll
  for (int s = 0; s < NSTRIPS; ++s) {
    pm = fmaxf(pm, posP[s * NROWS + row]);
    ns += sumP[s * NROWS + row];
  }
  const bool valid = (pm > -1e29f) && (ns > 0.f);
  // pm is pos*log2(e); loss = -pos + ln(exp2(pm) + sum_neg exp(s))   (no shift needed)
  float loss = valid ? (logf(__builtin_amdgcn_exp2f(pm) + ns) - pm * LN2F) : 0.f;
  float cnt = valid ? 1.f : 0.f;
#pragma unroll
  for (int off = 1; off < 64; off <<= 1) {
    loss += __shfl_xor(loss, off, 64);
    cnt += __shfl_xor(cnt, off, 64);
  }
  if ((threadIdx.x & 63) == 0) {
    atomicAdd(&acc[0], loss);
    atomicAdd(&acc[1], cnt);
    __threadfence();                       // my adds visible before the counter bump
  }
  __syncthreads();
  if (threadIdx.x == 0) {
    const int prev = atomicAdd((int*)(acc + 2), 1);
    if (prev == (int)gridDim.x - 1) {      // last block finalizes
      const float L = atomicAdd(&acc[0], 0.f);   // coherent reads
      const float C = atomicAdd(&acc[1], 0.f);
      out[0] = L / fmaxf(C, 1.f);
    }
  }
}

// ---------------- Launch ----------------
extern "C" void kernel_launch(void* const* d_in, const int* in_sizes, int n_in,
                              void* d_out, int out_size, void* d_ws, size_t ws_size,
                              hipStream_t stream) {
  const float* emb = (const float*)d_in[0];
  const int* cats = (const int*)d_in[1];
  // d_in[2] (font_labels) is unused by the reference.
  float* out = (float*)d_out;

  char* ws = (char*)d_ws;
  float* accv = (float*)ws;                                  // loss, cnt, block counter
  unsigned short* ebf = (unsigned short*)(ws + 256);         // 4 MB bf16 normalized
  float* posP = (float*)(ws + 256 + NROWS * DDIM * 2);       // 16 strips x 8192
  float* sumP = posP + NSTRIPS * NROWS;

  hipMemsetAsync(accv, 0, 16, stream);
  knorm<<<NROWS / 4, 256, 0, stream>>>(emb, ebf);
  kmain<<<dim3(NSTRIPS, NROWS / BM), 256, 0, stream>>>(ebf, cats, posP, sumP);
  kmerge<<<NROWS / 256, 256, 0, stream>>>(posP, sumP, accv, out);
}

// Round 5
// 118.319 us; speedup vs baseline: 2.9260x; 2.9260x over previous
//
#include <hip/hip_runtime.h>
#include <stdint.h>

// Problem constants (fixed by setup_inputs)
#define NROWS 8192
#define DDIM 256
#define NSTRIPS 16
#define STRIP_COLS 512     // NROWS / NSTRIPS
#define BN 32              // cols per LDS tile
#define NTILES 16          // STRIP_COLS / BN
#define BM 128             // rows per block (4 waves x 32 rows)

// Scores are computed directly in log2-units: e is scaled by sqrt(log2(e)/0.7)
// so acc = s*log2(e) and exp(s) == exp2(acc). Since s <= 1/0.7, exp2(acc) <= 4.17
// and per-row sums <= ~34k: no overflow, so NO log-sum-exp shift is needed at all.
#define ESCALE 1.4356159f        // sqrt(log2(e)/0.7)
#define LN2F   0.6931471806f
#define NEGBIG (-1e30f)

typedef __attribute__((ext_vector_type(8))) short short8;   // 8 bf16 = 4 VGPRs
typedef __attribute__((ext_vector_type(4))) float f32x4;    // MFMA 16x16 accumulator

typedef __attribute__((address_space(3))) void lds_void;          // LDS ptr for DMA builtin
typedef const __attribute__((address_space(1))) void gl_void;     // global ptr for DMA builtin

__device__ __forceinline__ unsigned short f2bf(float x) {   // RNE float->bf16
  unsigned int u = __float_as_uint(x);
  u += 0x7fffu + ((u >> 16) & 1u);
  return (unsigned short)(u >> 16);
}

// ---------------- Kernel 1: row L2-normalize -> scaled bf16 ----------------
__global__ __launch_bounds__(256) void knorm(const float* __restrict__ emb,
                                             unsigned short* __restrict__ ebf) {
  const int wave = threadIdx.x >> 6, lane = threadIdx.x & 63;
  const int row = blockIdx.x * 4 + wave;              // one wave per row
  const float4 v = *(const float4*)(emb + row * DDIM + lane * 4);
  float ss = v.x * v.x + v.y * v.y + v.z * v.z + v.w * v.w;
#pragma unroll
  for (int off = 1; off < 64; off <<= 1) ss += __shfl_xor(ss, off, 64);
  const float sc = rsqrtf(ss) * ESCALE;
  ushort4 o;
  o.x = f2bf(v.x * sc); o.y = f2bf(v.y * sc);
  o.z = f2bf(v.z * sc); o.w = f2bf(v.w * sc);
  *(ushort4*)(ebf + row * DDIM + lane * 4) = o;
}

// ---------------- Kernel 2: fused sims + masked max / sum-of-exp ----------------
// grid = (NSTRIPS, NROWS/BM) = 1024 blocks. LDS = 2 x 16 KB -> 5 blocks/CU.
// NO min-waves launch bound: R4 proved __launch_bounds__(256,5) forces VGPR=48 and
// spills a[2][8] to scratch (452 MB of HBM writes, 284us). Unconstrained = 80 VGPR,
// which already supports 6 waves/SIMD -- LDS is the binding limit, as intended.
// Depth-1 prefetch: STAGE(t+1) after the barrier overlaps compute(t); syncthreads'
// implicit vmcnt(0) only drains tile t's DMAs. T5 setprio around the MFMA cluster:
// 5 free-running blocks/CU give the scheduler wave role-diversity to arbitrate.
__global__ __launch_bounds__(256) void kmain(const unsigned short* __restrict__ ebf,
                                             const int* __restrict__ cats,
                                             float* __restrict__ posP,
                                             float* __restrict__ sumP) {
  // B tile: BN cols x 256 k as 16B chunks, chunk p = kc*32 + col at byte p*16.
  __shared__ alignas(16) unsigned short smem[2][BN * DDIM];  // 2 x 16 KB
  const int tid = threadIdx.x;
  const int lane = tid & 63, wave = tid >> 6;
  const int lane15 = lane & 15, quad = lane >> 4;
  const int strip = blockIdx.x, rowTile = blockIdx.y;
  const int rowG = rowTile * BM + wave * 32;          // this wave's 32 rows (m=2)
  const int col0 = strip * STRIP_COLS;

  // A fragments for the whole kernel live in registers: a[m][kk] covers
  // rows rowG+m*16+(lane&15), k = kk*32 + quad*8 .. +7   (64 VGPRs)
  short8 a[2][8];
#pragma unroll
  for (int m = 0; m < 2; ++m)
#pragma unroll
    for (int kk = 0; kk < 8; ++kk)
      a[m][kk] = *(const short8*)(ebf + (rowG + m * 16 + lane15) * DDIM + kk * 32 + quad * 8);

  // Per-lane C-layout row categories: row = quad*4 + r (+ m*16)
  int cati[2][4];
#pragma unroll
  for (int m = 0; m < 2; ++m)
#pragma unroll
    for (int r = 0; r < 4; ++r)
      cati[m][r] = cats[rowG + m * 16 + quad * 4 + r];

  // Is this lane the diagonal element (row==col) within a diagonal 16x16 tile?
  bool dlr[4];
#pragma unroll
  for (int r = 0; r < 4; ++r) dlr[r] = (lane15 == quad * 4 + r);

  float pm[2][4], ns[2][4];
#pragma unroll
  for (int m = 0; m < 2; ++m)
#pragma unroll
    for (int r = 0; r < 4; ++r) { pm[m][r] = NEGBIG; ns[m][r] = 0.f; }

  // Async-stage one B tile (1024 16B chunks) into buffer `buf`: 4 DMA per thread.
  // Thread (w,l) takes chunks p = c*256 + w*64 + l; LDS byte = p*16 decomposes as
  // wave-uniform (c*4096 + w*1024) + l*16. Global: kc = c*8 + w*2 + (l>>5), col = l&31.
#define STAGE(t, buf)                                                           \
  {                                                                             \
    const unsigned short* g = ebf +                                             \
        (size_t)(col0 + (t) * BN + (lane & 31)) * DDIM +                        \
        (wave * 2 + (lane >> 5)) * 8;                                           \
    char* lb = (char*)&smem[(buf)][0] + wave * 1024;                            \
    _Pragma("unroll")                                                           \
    for (int c = 0; c < 4; ++c)                                                 \
      __builtin_amdgcn_global_load_lds((gl_void*)(g + c * 64),                  \
                                       (lds_void*)(lb + c * 4096), 16, 0, 0);   \
  }

  STAGE(0, 0);

  for (int t = 0; t < NTILES; ++t) {
    __syncthreads();                       // tile t's DMA drained; prev reads done
    if (t + 1 < NTILES) STAGE(t + 1, (t + 1) & 1);   // overlaps this tile's MFMA
    const char* bb = (const char*)&smem[t & 1][0];
    const int colBase = col0 + t * BN;
    const int cjt[2] = {cats[colBase + lane15], cats[colBase + 16 + lane15]};

#pragma unroll
    for (int nt = 0; nt < 2; ++nt) {
      // Batch the 8 B-fragment reads ahead of the MFMA cluster: one latency +
      // pipelined ds_reads instead of a serial read->use chain.
      short8 b[8];
#pragma unroll
      for (int kk = 0; kk < 8; ++kk)
        b[kk] = *(const short8*)(bb + kk * 2048 + quad * 512 + nt * 256 + lane15 * 16);
      f32x4 acc0 = {0.f, 0.f, 0.f, 0.f}, acc1 = {0.f, 0.f, 0.f, 0.f};
      __builtin_amdgcn_s_setprio(1);       // T5: favor MFMA-issuing wave
#pragma unroll
      for (int kk = 0; kk < 8; ++kk) {
        acc0 = __builtin_amdgcn_mfma_f32_16x16x32_bf16(a[0][kk], b[kk], acc0, 0, 0, 0);
        acc1 = __builtin_amdgcn_mfma_f32_16x16x32_bf16(a[1][kk], b[kk], acc1, 0, 0, 0);
      }
      __builtin_amdgcn_s_setprio(0);
      const int cj = cjt[nt];
      // Wave-uniform: does this 16x16 tile sit on the global diagonal?
      const bool dg0 = (rowG == colBase + nt * 16);
      const bool dg1 = (rowG + 16 == colBase + nt * 16);
#pragma unroll
      for (int m = 0; m < 2; ++m) {
        const bool dg = m ? dg1 : dg0;
#pragma unroll
        for (int r = 0; r < 4; ++r) {
          const float s = m ? acc1[r] : acc0[r];      // score in log2-units
          const float e = __builtin_amdgcn_exp2f(s);
          const bool same = (cj == cati[m][r]);
          float psv = same ? s : NEGBIG;              // positive candidate
          if (dg) psv = dlr[r] ? NEGBIG : psv;        // exclude self (rare branch)
          pm[m][r] = fmaxf(pm[m][r], psv);
          ns[m][r] += same ? 0.f : e;                 // negative sum-of-exp
        }
      }
    }
  }

  // Reduce across the 16 lanes of each quad (they share rows quad*4+r).
#pragma unroll
  for (int off = 1; off < 16; off <<= 1) {
#pragma unroll
    for (int m = 0; m < 2; ++m)
#pragma unroll
      for (int r = 0; r < 4; ++r) {
        pm[m][r] = fmaxf(pm[m][r], __shfl_xor(pm[m][r], off, 64));
        ns[m][r] += __shfl_xor(ns[m][r], off, 64);
      }
  }
  if (lane15 == 0) {
#pragma unroll
    for (int m = 0; m < 2; ++m)
#pragma unroll
      for (int r = 0; r < 4; ++r) {
        const int row = rowG + m * 16 + quad * 4 + r;
        posP[strip * NROWS + row] = pm[m][r];
        sumP[strip * NROWS + row] = ns[m][r];
      }
  }
}

// ---------------- Kernel 3: merge strips, per-row loss, reduce, finalize ----------------
__global__ __launch_bounds__(256) void kmerge(const float* __restrict__ posP,
                                              const float* __restrict__ sumP,
                                              float* __restrict__ acc,
                                              float* __restrict__ out) {
  const int row = blockIdx.x * 256 + threadIdx.x;
  float pm = NEGBIG, ns = 0.f;
#pragma unroll
  for (int s = 0; s < NSTRIPS; ++s) {
    pm = fmaxf(pm, posP[s * NROWS + row]);
    ns += sumP[s * NROWS + row];
  }
  const bool valid = (pm > -1e29f) && (ns > 0.f);
  // pm is pos*log2(e); loss = -pos + ln(exp2(pm) + sum_neg exp(s))   (no shift needed)
  float loss = valid ? (logf(__builtin_amdgcn_exp2f(pm) + ns) - pm * LN2F) : 0.f;
  float cnt = valid ? 1.f : 0.f;
#pragma unroll
  for (int off = 1; off < 64; off <<= 1) {
    loss += __shfl_xor(loss, off, 64);
    cnt += __shfl_xor(cnt, off, 64);
  }
  if ((threadIdx.x & 63) == 0) {
    atomicAdd(&acc[0], loss);
    atomicAdd(&acc[1], cnt);
    __threadfence();                       // my adds visible before the counter bump
  }
  __syncthreads();
  if (threadIdx.x == 0) {
    const int prev = atomicAdd((int*)(acc + 2), 1);
    if (prev == (int)gridDim.x - 1) {      // last block finalizes
      const float L = atomicAdd(&acc[0], 0.f);   // coherent reads
      const float C = atomicAdd(&acc[1], 0.f);
      out[0] = L / fmaxf(C, 1.f);
    }
  }
}

// ---------------- Launch ----------------
extern "C" void kernel_launch(void* const* d_in, const int* in_sizes, int n_in,
                              void* d_out, int out_size, void* d_ws, size_t ws_size,
                              hipStream_t stream) {
  const float* emb = (const float*)d_in[0];
  const int* cats = (const int*)d_in[1];
  // d_in[2] (font_labels) is unused by the reference.
  float* out = (float*)d_out;

  char* ws = (char*)d_ws;
  float* accv = (float*)ws;                                  // loss, cnt, block counter
  unsigned short* ebf = (unsigned short*)(ws + 256);         // 4 MB bf16 normalized
  float* posP = (float*)(ws + 256 + NROWS * DDIM * 2);       // 16 strips x 8192
  float* sumP = posP + NSTRIPS * NROWS;

  hipMemsetAsync(accv, 0, 16, stream);
  knorm<<<NROWS / 4, 256, 0, stream>>>(emb, ebf);
  kmain<<<dim3(NSTRIPS, NROWS / BM), 256, 0, stream>>>(ebf, cats, posP, sumP);
  kmerge<<<NROWS / 256, 256, 0, stream>>>(posP, sumP, accv, out);
}